// Round 3
// baseline (1121.084 us; speedup 1.0000x reference)
//
#include <hip/hip_runtime.h>
#include <math.h>

#define H  14
#define C  7
#define HC 98
#define FIN 256
#define NEG_SLOPE 0.2f
#define NODES_PER_BLOCK 16
#define AGG_BLOCK (NODES_PER_BLOCK * H)   // 224 threads

__device__ __forceinline__ float sanitize(float v) {
    return isfinite(v) ? v : 0.f;
}

// ---------------- CSR construction ----------------

__global__ void k_deg_init(int* __restrict__ deg, int N) {
    int i = blockIdx.x * blockDim.x + threadIdx.x;
    if (i < N) deg[i] = 1;              // self loop
}

__global__ void k_deg_count(const int* __restrict__ ei, int E, int* __restrict__ deg) {
    int e = blockIdx.x * blockDim.x + threadIdx.x;
    if (e < E) atomicAdd(deg + ei[E + e], 1);
}

// per-block inclusive scan (1024/block); row_ptr[i+1]=within-block inclusive, bsum[b]=block total
__global__ __launch_bounds__(1024) void k_scanA(const int* __restrict__ deg,
                                                int* __restrict__ row_ptr,
                                                int* __restrict__ bsum, int N) {
    __shared__ int sd[1024];
    int t = threadIdx.x;
    int i = blockIdx.x * 1024 + t;
    sd[t] = (i < N) ? deg[i] : 0;
    __syncthreads();
    #pragma unroll
    for (int off = 1; off < 1024; off <<= 1) {
        int v = (t >= off) ? sd[t - off] : 0;
        __syncthreads();
        sd[t] += v;
        __syncthreads();
    }
    if (i < N) row_ptr[i + 1] = sd[t];
    if (t == 1023) bsum[blockIdx.x] = sd[t];
}

// single-block inclusive scan of block sums (nb <= 1024)
__global__ __launch_bounds__(1024) void k_scanB(int* __restrict__ bsum, int nb) {
    __shared__ int sd[1024];
    int t = threadIdx.x;
    sd[t] = (t < nb) ? bsum[t] : 0;
    __syncthreads();
    #pragma unroll
    for (int off = 1; off < 1024; off <<= 1) {
        int v = (t >= off) ? sd[t - off] : 0;
        __syncthreads();
        sd[t] += v;
        __syncthreads();
    }
    if (t < nb) bsum[t] = sd[t];
}

// add block offsets; row_ptr[0] = 0
__global__ void k_scanC(int* __restrict__ row_ptr, const int* __restrict__ bsum, int N) {
    int i = blockIdx.x * blockDim.x + threadIdx.x;
    if (i == 0) row_ptr[0] = 0;
    if (i < N) {
        int b = i >> 10;
        if (b > 0) row_ptr[i + 1] += bsum[b - 1];
    }
}

__global__ void k_cursor(const int* __restrict__ row_ptr, int* __restrict__ cursor, int N) {
    int i = blockIdx.x * blockDim.x + threadIdx.x;
    if (i < N) cursor[i] = row_ptr[i];
}

__global__ void k_scatter(const int* __restrict__ ei, int E, int ET,
                          int* __restrict__ cursor, int* __restrict__ col) {
    int e = blockIdx.x * blockDim.x + threadIdx.x;
    if (e >= ET) return;
    int s, d;
    if (e < E) { s = ei[e]; d = ei[E + e]; } else { s = e - E; d = s; }
    int pos = atomicAdd(cursor + d, 1);
    col[pos] = s;
}

// ---------------- projections (all f32) ----------------

// layer-1: xh = x @ W1 (256 -> 98) + per-head logits
__global__ __launch_bounds__(128) void k_proj1(
    const float* __restrict__ x, const float* __restrict__ W,
    const float* __restrict__ asrc, const float* __restrict__ adst,
    float* __restrict__ xh, float* __restrict__ alsrc, float* __restrict__ aldst)
{
    __shared__ float xrow[FIN];
    __shared__ float row[HC];
    const int n = blockIdx.x;
    const int t = threadIdx.x;
    const float* xp = x + (size_t)n * FIN;
    xrow[t]       = sanitize(xp[t]);
    xrow[t + 128] = sanitize(xp[t + 128]);
    __syncthreads();
    if (t < HC) {
        float acc = 0.f;
        #pragma unroll 8
        for (int k = 0; k < FIN; ++k)
            acc = fmaf(xrow[k], W[k * HC + t], acc);
        acc = sanitize(acc);
        xh[(size_t)n * HC + t] = acc;
        row[t] = acc;
    }
    __syncthreads();
    if (t < H) {
        float s1 = 0.f, s2 = 0.f;
        #pragma unroll
        for (int c2 = 0; c2 < C; ++c2) {
            float v = row[t * C + c2];
            s1 = fmaf(v, asrc[t * C + c2], s1);
            s2 = fmaf(v, adst[t * C + c2], s2);
        }
        alsrc[(size_t)n * H + t] = sanitize(s1);
        aldst[(size_t)n * H + t] = sanitize(s2);
    }
}

// layer-2: xh = h1 @ W2 (7 -> 98) + logits
__global__ __launch_bounds__(128) void k_proj2(
    const float* __restrict__ h1, const float* __restrict__ W,
    const float* __restrict__ asrc, const float* __restrict__ adst,
    float* __restrict__ xh, float* __restrict__ alsrc, float* __restrict__ aldst)
{
    __shared__ float xrow[C];
    __shared__ float row[HC];
    const int n = blockIdx.x;
    const int t = threadIdx.x;
    if (t < C) xrow[t] = h1[(size_t)n * C + t];
    __syncthreads();
    if (t < HC) {
        float acc = 0.f;
        #pragma unroll
        for (int k = 0; k < C; ++k)
            acc = fmaf(xrow[k], W[k * HC + t], acc);
        acc = sanitize(acc);
        xh[(size_t)n * HC + t] = acc;
        row[t] = acc;
    }
    __syncthreads();
    if (t < H) {
        float s1 = 0.f, s2 = 0.f;
        #pragma unroll
        for (int c2 = 0; c2 < C; ++c2) {
            float v = row[t * C + c2];
            s1 = fmaf(v, asrc[t * C + c2], s1);
            s2 = fmaf(v, adst[t * C + c2], s2);
        }
        alsrc[(size_t)n * H + t] = sanitize(s1);
        aldst[(size_t)n * H + t] = sanitize(s2);
    }
}

// ---------------- fused aggregation ----------------
// thread = (node, head); online softmax-max over in-edges; LDS head-mean;
// LAYER 1: +bias, relu -> h1[N,7] ; LAYER 2: log_softmax -> f32 out[N,7]
template<int LAYER>
__global__ __launch_bounds__(AGG_BLOCK) void k_agg(
    const int* __restrict__ row_ptr, const int* __restrict__ col,
    const float* __restrict__ xh, const float* __restrict__ alsrc,
    const float* __restrict__ aldst, const float* __restrict__ bias,
    float* __restrict__ h1, float* __restrict__ out, int N)
{
    __shared__ float vals[NODES_PER_BLOCK][HC];
    __shared__ float fv[NODES_PER_BLOCK][C];
    const int t  = threadIdx.x;
    const int nl = t / H;
    const int h  = t - nl * H;
    const int n  = blockIdx.x * NODES_PER_BLOCK + nl;

    if (n < N) {
        const int e0 = row_ptr[n], e1 = row_ptr[n + 1];
        const float ld = aldst[(size_t)n * H + h];
        float m, den, mx[C];
        {   // first edge (every node has >= 1: its self loop)
            int s = col[e0];
            float l = alsrc[(size_t)s * H + h] + ld;
            l = (l > 0.f) ? l : NEG_SLOPE * l;
            m = l; den = 1.f;
            const float* xp = xh + (size_t)s * HC + h * C;
            #pragma unroll
            for (int c2 = 0; c2 < C; ++c2) mx[c2] = xp[c2];
        }
        for (int e = e0 + 1; e < e1; ++e) {
            int s = col[e];
            float l = alsrc[(size_t)s * H + h] + ld;
            l = (l > 0.f) ? l : NEG_SLOPE * l;
            float mn = fmaxf(m, l);
            float r  = __expf(m - mn);
            float p  = __expf(l - mn);
            den = den * r + p;
            const float* xp = xh + (size_t)s * HC + h * C;
            #pragma unroll
            for (int c2 = 0; c2 < C; ++c2) mx[c2] = fmaxf(mx[c2] * r, p * xp[c2]);
            m = mn;
        }
        float rd = 1.f / den;
        #pragma unroll
        for (int c2 = 0; c2 < C; ++c2) vals[nl][h * C + c2] = mx[c2] * rd;
    }
    __syncthreads();

    if (t < NODES_PER_BLOCK * C) {
        int nl2 = t / C, c2 = t - nl2 * C;
        int n2 = blockIdx.x * NODES_PER_BLOCK + nl2;
        if (n2 < N) {
            float s = 0.f;
            #pragma unroll
            for (int hh = 0; hh < H; ++hh) s += vals[nl2][hh * C + c2];
            float o = s * (1.f / H) + bias[c2];
            if (LAYER == 1) h1[(size_t)n2 * C + c2] = fmaxf(o, 0.f);
            else            fv[nl2][c2] = o;
        }
    }
    if (LAYER == 2) {
        __syncthreads();
        if (t < NODES_PER_BLOCK) {
            int n2 = blockIdx.x * NODES_PER_BLOCK + t;
            if (n2 < N) {
                float mv = -1e30f;
                #pragma unroll
                for (int c2 = 0; c2 < C; ++c2) mv = fmaxf(mv, fv[t][c2]);
                float lse = 0.f;
                #pragma unroll
                for (int c2 = 0; c2 < C; ++c2) lse += __expf(fv[t][c2] - mv);
                lse = logf(lse);
                #pragma unroll
                for (int c2 = 0; c2 < C; ++c2)
                    out[(size_t)n2 * C + c2] = fv[t][c2] - mv - lse;
            }
        }
    }
}

// ---------------- launch ----------------

extern "C" void kernel_launch(void* const* d_in, const int* in_sizes, int n_in,
                              void* d_out, int out_size, void* d_ws, size_t ws_size,
                              hipStream_t stream)
{
    const float* x     = (const float*)d_in[0];
    const int*   ei    = (const int*)d_in[1];
    const float* W1    = (const float*)d_in[2];
    const float* asrc1 = (const float*)d_in[3];
    const float* adst1 = (const float*)d_in[4];
    const float* b1    = (const float*)d_in[5];
    const float* W2    = (const float*)d_in[6];
    const float* asrc2 = (const float*)d_in[7];
    const float* adst2 = (const float*)d_in[8];
    const float* b2    = (const float*)d_in[9];

    const int N  = in_sizes[0] / FIN;   // 100000
    const int E  = in_sizes[1] / 2;     // 1600000
    const int ET = E + N;

    char* w = (char*)d_ws;
    float* xh      = (float*)w; w += (size_t)N * HC * 4;   // 39.2 MB
    float* alsrc   = (float*)w; w += (size_t)N * H * 4;    //  5.6 MB
    float* aldst   = (float*)w; w += (size_t)N * H * 4;    //  5.6 MB
    float* h1      = (float*)w; w += (size_t)N * C * 4;    //  2.8 MB
    int*   row_ptr = (int*)w;   w += (size_t)(N + 1) * 4;
    int*   deg     = (int*)w;   w += (size_t)N * 4;
    int*   cursor  = (int*)w;   w += (size_t)N * 4;
    int*   col     = (int*)w;   w += (size_t)ET * 4;       //  6.8 MB
    int*   bsum    = (int*)w;   w += 1024 * 4;             // total ~61 MB

    const int g256N  = (N + 255) / 256;
    const int g256E  = (E + 255) / 256;
    const int g256ET = (ET + 255) / 256;
    const int nbA    = (N + 1023) / 1024;
    const int gAgg   = (N + NODES_PER_BLOCK - 1) / NODES_PER_BLOCK;

    // CSR build (graph identical across layers; rebuilt each call — no state)
    k_deg_init<<<g256N, 256, 0, stream>>>(deg, N);
    k_deg_count<<<g256E, 256, 0, stream>>>(ei, E, deg);
    k_scanA<<<nbA, 1024, 0, stream>>>(deg, row_ptr, bsum, N);
    k_scanB<<<1, 1024, 0, stream>>>(bsum, nbA);
    k_scanC<<<g256N, 256, 0, stream>>>(row_ptr, bsum, N);
    k_cursor<<<g256N, 256, 0, stream>>>(row_ptr, cursor, N);
    k_scatter<<<g256ET, 256, 0, stream>>>(ei, E, ET, cursor, col);

    // layer 1
    k_proj1<<<N, 128, 0, stream>>>(x, W1, asrc1, adst1, xh, alsrc, aldst);
    k_agg<1><<<gAgg, AGG_BLOCK, 0, stream>>>(row_ptr, col, xh, alsrc, aldst, b1,
                                             h1, (float*)d_out, N);
    // layer 2
    k_proj2<<<N, 128, 0, stream>>>(h1, W2, asrc2, adst2, xh, alsrc, aldst);
    k_agg<2><<<gAgg, AGG_BLOCK, 0, stream>>>(row_ptr, col, xh, alsrc, aldst, b2,
                                             h1, (float*)d_out, N);
}

// Round 4
// 730.266 us; speedup vs baseline: 1.5352x; 1.5352x over previous
//
#include <hip/hip_runtime.h>
#include <math.h>

#define H  14
#define C  7
#define HC 98
#define FIN 256
#define NEG_SLOPE 0.2f
#define NODES_PER_BLOCK 16
#define AGG_BLOCK (NODES_PER_BLOCK * H)   // 224 threads

typedef __attribute__((ext_vector_type(8))) short short8;
typedef __attribute__((ext_vector_type(4))) float floatx4;

#define WT_ROWS   112            // 98 cols zero-padded to 7*16
#define WT_STRIDE 264            // 256 + 8 pad (bf16 units) -> bank-friendly
#define XA_STRIDE 40             // 32 + 8 pad (bf16 units)

// ---------------- CSR construction ----------------

__global__ void k_deg_init(int* __restrict__ deg, int N) {
    int i = blockIdx.x * blockDim.x + threadIdx.x;
    if (i < N) deg[i] = 1;              // self loop
}

__global__ void k_deg_count(const int* __restrict__ ei, int E, int* __restrict__ deg) {
    int e = blockIdx.x * blockDim.x + threadIdx.x;
    if (e < E) atomicAdd(deg + ei[E + e], 1);
}

__global__ __launch_bounds__(1024) void k_scanA(const int* __restrict__ deg,
                                                int* __restrict__ row_ptr,
                                                int* __restrict__ bsum, int N) {
    __shared__ int sd[1024];
    int t = threadIdx.x;
    int i = blockIdx.x * 1024 + t;
    sd[t] = (i < N) ? deg[i] : 0;
    __syncthreads();
    #pragma unroll
    for (int off = 1; off < 1024; off <<= 1) {
        int v = (t >= off) ? sd[t - off] : 0;
        __syncthreads();
        sd[t] += v;
        __syncthreads();
    }
    if (i < N) row_ptr[i + 1] = sd[t];
    if (t == 1023) bsum[blockIdx.x] = sd[t];
}

__global__ __launch_bounds__(1024) void k_scanB(int* __restrict__ bsum, int nb) {
    __shared__ int sd[1024];
    int t = threadIdx.x;
    sd[t] = (t < nb) ? bsum[t] : 0;
    __syncthreads();
    #pragma unroll
    for (int off = 1; off < 1024; off <<= 1) {
        int v = (t >= off) ? sd[t - off] : 0;
        __syncthreads();
        sd[t] += v;
        __syncthreads();
    }
    if (t < nb) bsum[t] = sd[t];
}

__global__ void k_scanC(int* __restrict__ row_ptr, const int* __restrict__ bsum, int N) {
    int i = blockIdx.x * blockDim.x + threadIdx.x;
    if (i == 0) row_ptr[0] = 0;
    if (i < N) {
        int b = i >> 10;
        if (b > 0) row_ptr[i + 1] += bsum[b - 1];
    }
}

__global__ void k_cursor(const int* __restrict__ row_ptr, int* __restrict__ cursor, int N) {
    int i = blockIdx.x * blockDim.x + threadIdx.x;
    if (i < N) cursor[i] = row_ptr[i];
}

__global__ void k_scatter(const int* __restrict__ ei, int E, int ET,
                          int* __restrict__ cursor, int* __restrict__ col) {
    int e = blockIdx.x * blockDim.x + threadIdx.x;
    if (e >= ET) return;
    int s, d;
    if (e < E) { s = ei[e]; d = ei[E + e]; } else { s = e - E; d = s; }
    int pos = atomicAdd(cursor + d, 1);
    col[pos] = s;
}

// ---------------- layer-1 projection via MFMA ----------------

// W1 [256][98] f32  ->  Wt bf16 [112][256] (transposed, zero-padded cols)
__global__ void k_convW(const float* __restrict__ W, unsigned short* __restrict__ WtG) {
    int id = blockIdx.x * blockDim.x + threadIdx.x;   // 112*256
    int n = id >> 8, k = id & 255;
    float v = (n < HC) ? W[k * HC + n] : 0.f;
    WtG[id] = (unsigned short)(__float_as_uint(v) >> 16);  // exact: inputs bf16-rounded
}

// xh[rows 64b..][98] = x @ W1 using mfma_f32_16x16x32_bf16
// block: 256 thr = 4 waves; wave w -> rows 16w..16w+15; 7 col-tiles of 16 (98 used)
__global__ __launch_bounds__(256) void k_proj1_mfma(
    const float* __restrict__ x, const unsigned short* __restrict__ WtG,
    float* __restrict__ xh, int N)
{
    __shared__ unsigned short wt_s[WT_ROWS * WT_STRIDE];  // 59136 B
    __shared__ unsigned short xa_s[64 * XA_STRIDE];       //  5120 B
    const int t  = threadIdx.x;
    const int wv = t >> 6;
    const int l  = t & 63;
    const int ln = l & 15;
    const int qd = l >> 4;
    const int rowBase = blockIdx.x * 64;

    // stage Wt (unpadded [112][256] global -> padded stride in LDS)
    #pragma unroll
    for (int i = 0; i < 14; ++i) {
        int f = i * 256 + t;            // uint4 index, 3584 total (32 per row)
        int r = f >> 5, pos = f & 31;
        *(uint4*)(wt_s + r * WT_STRIDE + pos * 8) = ((const uint4*)WtG)[f];
    }

    floatx4 acc[7] = {};

    for (int step = 0; step < 8; ++step) {
        const int k0 = step * 32;
        __syncthreads();                 // xa_s reuse (also orders wt_s stage once)
        // stage A: 64 rows x 32 k, f32 -> bf16 (truncation exact on bf16-rounded data)
        #pragma unroll
        for (int i = 0; i < 2; ++i) {
            int idx = i * 256 + t;       // 512 float4 total
            int r = idx >> 3, c4 = idx & 7;
            int gr = rowBase + r; if (gr >= N) gr = N - 1;
            float4 v = *(const float4*)(x + (size_t)gr * FIN + k0 + c4 * 4);
            ushort4 u;
            u.x = (unsigned short)(__float_as_uint(v.x) >> 16);
            u.y = (unsigned short)(__float_as_uint(v.y) >> 16);
            u.z = (unsigned short)(__float_as_uint(v.z) >> 16);
            u.w = (unsigned short)(__float_as_uint(v.w) >> 16);
            *(ushort4*)(xa_s + r * XA_STRIDE + c4 * 4) = u;
        }
        __syncthreads();
        // A frag: A[m=ln][k=qd*8+j]  (8 contiguous bf16 -> ds_read_b128)
        short8 a = *(const short8*)(xa_s + ((wv << 4) + ln) * XA_STRIDE + qd * 8);
        #pragma unroll
        for (int ct = 0; ct < 7; ++ct) {
            short8 b = *(const short8*)(wt_s + (ct * 16 + ln) * WT_STRIDE + k0 + qd * 8);
            acc[ct] = __builtin_amdgcn_mfma_f32_16x16x32_bf16(a, b, acc[ct], 0, 0, 0);
        }
    }

    // C/D: col = ln, row = qd*4 + r (within the wave's 16-row tile)
    #pragma unroll
    for (int ct = 0; ct < 7; ++ct) {
        #pragma unroll
        for (int r = 0; r < 4; ++r) {
            int gr   = rowBase + (wv << 4) + (qd << 2) + r;
            int colg = ct * 16 + ln;
            if (gr < N && colg < HC)
                xh[(size_t)gr * HC + colg] = acc[ct][r];
        }
    }
}

// per-(node,head) attention logits from xh
__global__ void k_logits(const float* __restrict__ xh,
                         const float* __restrict__ asrc, const float* __restrict__ adst,
                         float* __restrict__ alsrc, float* __restrict__ aldst, int NH)
{
    int id = blockIdx.x * blockDim.x + threadIdx.x;
    if (id >= NH) return;
    int h = id % H;
    const float* xp = xh + (size_t)(id / H) * HC + h * C;
    float s1 = 0.f, s2 = 0.f;
    #pragma unroll
    for (int c2 = 0; c2 < C; ++c2) {
        float v = xp[c2];
        s1 = fmaf(v, asrc[h * C + c2], s1);
        s2 = fmaf(v, adst[h * C + c2], s2);
    }
    alsrc[id] = s1;
    aldst[id] = s2;
}

// ---------------- layer-2 projection (K=7, VALU) ----------------

__global__ __launch_bounds__(128) void k_proj2(
    const float* __restrict__ h1, const float* __restrict__ W,
    const float* __restrict__ asrc, const float* __restrict__ adst,
    float* __restrict__ xh, float* __restrict__ alsrc, float* __restrict__ aldst)
{
    __shared__ float xrow[C];
    __shared__ float row[HC];
    const int n = blockIdx.x;
    const int t = threadIdx.x;
    if (t < C) xrow[t] = h1[(size_t)n * C + t];
    __syncthreads();
    if (t < HC) {
        float acc = 0.f;
        #pragma unroll
        for (int k = 0; k < C; ++k)
            acc = fmaf(xrow[k], W[k * HC + t], acc);
        xh[(size_t)n * HC + t] = acc;
        row[t] = acc;
    }
    __syncthreads();
    if (t < H) {
        float s1 = 0.f, s2 = 0.f;
        #pragma unroll
        for (int c2 = 0; c2 < C; ++c2) {
            float v = row[t * C + c2];
            s1 = fmaf(v, asrc[t * C + c2], s1);
            s2 = fmaf(v, adst[t * C + c2], s2);
        }
        alsrc[(size_t)n * H + t] = s1;
        aldst[(size_t)n * H + t] = s2;
    }
}

// ---------------- fused aggregation ----------------

template<int LAYER>
__global__ __launch_bounds__(AGG_BLOCK) void k_agg(
    const int* __restrict__ row_ptr, const int* __restrict__ col,
    const float* __restrict__ xh, const float* __restrict__ alsrc,
    const float* __restrict__ aldst, const float* __restrict__ bias,
    float* __restrict__ h1, float* __restrict__ out, int N)
{
    __shared__ float vals[NODES_PER_BLOCK][HC];
    __shared__ float fv[NODES_PER_BLOCK][C];
    const int t  = threadIdx.x;
    const int nl = t / H;
    const int h  = t - nl * H;
    const int n  = blockIdx.x * NODES_PER_BLOCK + nl;

    if (n < N) {
        const int e0 = row_ptr[n], e1 = row_ptr[n + 1];
        const float ld = aldst[(size_t)n * H + h];
        float m, den, mx[C];
        {   // first edge (every node has >= 1: its self loop)
            int s = col[e0];
            float l = alsrc[(size_t)s * H + h] + ld;
            l = (l > 0.f) ? l : NEG_SLOPE * l;
            m = l; den = 1.f;
            const float* xp = xh + (size_t)s * HC + h * C;
            #pragma unroll
            for (int c2 = 0; c2 < C; ++c2) mx[c2] = xp[c2];
        }
        for (int e = e0 + 1; e < e1; ++e) {
            int s = col[e];
            float l = alsrc[(size_t)s * H + h] + ld;
            l = (l > 0.f) ? l : NEG_SLOPE * l;
            float mn = fmaxf(m, l);
            float r  = __expf(m - mn);
            float p  = __expf(l - mn);
            den = den * r + p;
            const float* xp = xh + (size_t)s * HC + h * C;
            #pragma unroll
            for (int c2 = 0; c2 < C; ++c2) mx[c2] = fmaxf(mx[c2] * r, p * xp[c2]);
            m = mn;
        }
        float rd = 1.f / den;
        #pragma unroll
        for (int c2 = 0; c2 < C; ++c2) vals[nl][h * C + c2] = mx[c2] * rd;
    }
    __syncthreads();

    if (t < NODES_PER_BLOCK * C) {
        int nl2 = t / C, c2 = t - nl2 * C;
        int n2 = blockIdx.x * NODES_PER_BLOCK + nl2;
        if (n2 < N) {
            float s = 0.f;
            #pragma unroll
            for (int hh = 0; hh < H; ++hh) s += vals[nl2][hh * C + c2];
            float o = s * (1.f / H) + bias[c2];
            if (LAYER == 1) h1[(size_t)n2 * C + c2] = fmaxf(o, 0.f);
            else            fv[nl2][c2] = o;
        }
    }
    if (LAYER == 2) {
        __syncthreads();
        if (t < NODES_PER_BLOCK) {
            int n2 = blockIdx.x * NODES_PER_BLOCK + t;
            if (n2 < N) {
                float mv = -1e30f;
                #pragma unroll
                for (int c2 = 0; c2 < C; ++c2) mv = fmaxf(mv, fv[t][c2]);
                float lse = 0.f;
                #pragma unroll
                for (int c2 = 0; c2 < C; ++c2) lse += __expf(fv[t][c2] - mv);
                lse = logf(lse);
                #pragma unroll
                for (int c2 = 0; c2 < C; ++c2)
                    out[(size_t)n2 * C + c2] = fv[t][c2] - mv - lse;
            }
        }
    }
}

// ---------------- launch ----------------

static inline size_t align16(size_t v) { return (v + 15) & ~(size_t)15; }

extern "C" void kernel_launch(void* const* d_in, const int* in_sizes, int n_in,
                              void* d_out, int out_size, void* d_ws, size_t ws_size,
                              hipStream_t stream)
{
    const float* x     = (const float*)d_in[0];
    const int*   ei    = (const int*)d_in[1];
    const float* W1    = (const float*)d_in[2];
    const float* asrc1 = (const float*)d_in[3];
    const float* adst1 = (const float*)d_in[4];
    const float* b1    = (const float*)d_in[5];
    const float* W2    = (const float*)d_in[6];
    const float* asrc2 = (const float*)d_in[7];
    const float* adst2 = (const float*)d_in[8];
    const float* b2    = (const float*)d_in[9];

    const int N  = in_sizes[0] / FIN;   // 100000
    const int E  = in_sizes[1] / 2;     // 1600000
    const int ET = E + N;

    char* w = (char*)d_ws;
    float* xh      = (float*)w; w += align16((size_t)N * HC * 4);
    float* alsrc   = (float*)w; w += align16((size_t)N * H * 4);
    float* aldst   = (float*)w; w += align16((size_t)N * H * 4);
    float* h1      = (float*)w; w += align16((size_t)N * C * 4);
    int*   row_ptr = (int*)w;   w += align16((size_t)(N + 1) * 4);
    int*   deg     = (int*)w;   w += align16((size_t)N * 4);
    int*   cursor  = (int*)w;   w += align16((size_t)N * 4);
    int*   col     = (int*)w;   w += align16((size_t)ET * 4);
    int*   bsum    = (int*)w;   w += align16(1024 * 4);
    unsigned short* WtG = (unsigned short*)w; w += align16((size_t)WT_ROWS * FIN * 2);

    const int g256N  = (N + 255) / 256;
    const int g256E  = (E + 255) / 256;
    const int g256ET = (ET + 255) / 256;
    const int nbA    = (N + 1023) / 1024;
    const int gAgg   = (N + NODES_PER_BLOCK - 1) / NODES_PER_BLOCK;
    const int gMfma  = (N + 63) / 64;
    const int gLog   = (N * H + 255) / 256;

    // CSR build (graph identical across layers; rebuilt each call — no state)
    k_deg_init<<<g256N, 256, 0, stream>>>(deg, N);
    k_deg_count<<<g256E, 256, 0, stream>>>(ei, E, deg);
    k_scanA<<<nbA, 1024, 0, stream>>>(deg, row_ptr, bsum, N);
    k_scanB<<<1, 1024, 0, stream>>>(bsum, nbA);
    k_scanC<<<g256N, 256, 0, stream>>>(row_ptr, bsum, N);
    k_cursor<<<g256N, 256, 0, stream>>>(row_ptr, cursor, N);
    k_scatter<<<g256ET, 256, 0, stream>>>(ei, E, ET, cursor, col);

    // layer 1 (MFMA projection)
    k_convW<<<(WT_ROWS * FIN + 255) / 256, 256, 0, stream>>>(W1, WtG);
    k_proj1_mfma<<<gMfma, 256, 0, stream>>>(x, WtG, xh, N);
    k_logits<<<gLog, 256, 0, stream>>>(xh, asrc1, adst1, alsrc, aldst, N * H);
    k_agg<1><<<gAgg, AGG_BLOCK, 0, stream>>>(row_ptr, col, xh, alsrc, aldst, b1,
                                             h1, (float*)d_out, N);
    // layer 2
    k_proj2<<<N, 128, 0, stream>>>(h1, W2, asrc2, adst2, xh, alsrc, aldst);
    k_agg<2><<<gAgg, AGG_BLOCK, 0, stream>>>(row_ptr, col, xh, alsrc, aldst, b2,
                                             h1, (float*)d_out, N);
}

// Round 5
// 609.012 us; speedup vs baseline: 1.8408x; 1.1991x over previous
//
#include <hip/hip_runtime.h>
#include <math.h>

#define H  14
#define C  7
#define HC 98
#define FIN 256
#define NEG_SLOPE 0.2f
#define NPB 32
#define AGG_BLOCK (NPB * H)   // 448 = 7 full waves

typedef __attribute__((ext_vector_type(8))) short short8;
typedef __attribute__((ext_vector_type(4))) float floatx4;

#define WT_ROWS   112            // 98 cols zero-padded to 7*16
#define WT_STRIDE 264            // 256 + 8 pad (bf16 units)
#define XA_STRIDE 40             // 32 + 8 pad (bf16 units)

// f32 -> bf16 bits, round-to-nearest-even
__device__ __forceinline__ unsigned bf16r(float f) {
    unsigned u = __float_as_uint(f);
    return (u + 0x7FFFu + ((u >> 16) & 1u)) >> 16;
}
__device__ __forceinline__ float bflo(unsigned w) { return __uint_as_float(w << 16); }
__device__ __forceinline__ float bfhi(unsigned w) { return __uint_as_float(w & 0xFFFF0000u); }

// ---------------- CSR construction ----------------

__global__ void k_deg_init(int* __restrict__ deg, int N) {
    int i = blockIdx.x * blockDim.x + threadIdx.x;
    if (i < N) deg[i] = 1;              // self loop
}

__global__ void k_deg_count(const int* __restrict__ ei, int E, int* __restrict__ deg) {
    int e = blockIdx.x * blockDim.x + threadIdx.x;
    if (e < E) atomicAdd(deg + ei[E + e], 1);
}

__global__ __launch_bounds__(1024) void k_scanA(const int* __restrict__ deg,
                                                int* __restrict__ row_ptr,
                                                int* __restrict__ bsum, int N) {
    __shared__ int sd[1024];
    int t = threadIdx.x;
    int i = blockIdx.x * 1024 + t;
    sd[t] = (i < N) ? deg[i] : 0;
    __syncthreads();
    #pragma unroll
    for (int off = 1; off < 1024; off <<= 1) {
        int v = (t >= off) ? sd[t - off] : 0;
        __syncthreads();
        sd[t] += v;
        __syncthreads();
    }
    if (i < N) row_ptr[i + 1] = sd[t];
    if (t == 1023) bsum[blockIdx.x] = sd[t];
}

__global__ __launch_bounds__(1024) void k_scanB(int* __restrict__ bsum, int nb) {
    __shared__ int sd[1024];
    int t = threadIdx.x;
    sd[t] = (t < nb) ? bsum[t] : 0;
    __syncthreads();
    #pragma unroll
    for (int off = 1; off < 1024; off <<= 1) {
        int v = (t >= off) ? sd[t - off] : 0;
        __syncthreads();
        sd[t] += v;
        __syncthreads();
    }
    if (t < nb) bsum[t] = sd[t];
}

__global__ void k_scanC(int* __restrict__ row_ptr, const int* __restrict__ bsum, int N) {
    int i = blockIdx.x * blockDim.x + threadIdx.x;
    if (i == 0) row_ptr[0] = 0;
    if (i < N) {
        int b = i >> 10;
        if (b > 0) row_ptr[i + 1] += bsum[b - 1];
    }
}

__global__ void k_cursor(const int* __restrict__ row_ptr, int* __restrict__ cursor, int N) {
    int i = blockIdx.x * blockDim.x + threadIdx.x;
    if (i < N) cursor[i] = row_ptr[i];
}

__global__ void k_scatter(const int* __restrict__ ei, int E, int ET,
                          int* __restrict__ cursor, int* __restrict__ col) {
    int e = blockIdx.x * blockDim.x + threadIdx.x;
    if (e >= ET) return;
    int s, d;
    if (e < E) { s = ei[e]; d = ei[E + e]; } else { s = e - E; d = s; }
    int pos = atomicAdd(cursor + d, 1);
    col[pos] = s;
}

// ---------------- layer-1 projection via MFMA ----------------

// W1 [256][98] f32  ->  Wt bf16 [112][256] (transposed, zero-padded cols)
__global__ void k_convW(const float* __restrict__ W, unsigned short* __restrict__ WtG) {
    int id = blockIdx.x * blockDim.x + threadIdx.x;   // 112*256
    int n = id >> 8, k = id & 255;
    float v = (n < HC) ? W[k * HC + n] : 0.f;
    WtG[id] = (unsigned short)(__float_as_uint(v) >> 16);  // exact: inputs bf16-rounded
}

// xhb(bf16)[N][98] = x @ W1 using mfma_f32_16x16x32_bf16
__global__ __launch_bounds__(256) void k_proj1_mfma(
    const float* __restrict__ x, const unsigned short* __restrict__ WtG,
    unsigned short* __restrict__ xhb, int N)
{
    __shared__ unsigned short wt_s[WT_ROWS * WT_STRIDE];  // 59136 B
    __shared__ unsigned short xa_s[64 * XA_STRIDE];       //  5120 B
    const int t  = threadIdx.x;
    const int wv = t >> 6;
    const int l  = t & 63;
    const int ln = l & 15;
    const int qd = l >> 4;
    const int rowBase = blockIdx.x * 64;

    #pragma unroll
    for (int i = 0; i < 14; ++i) {
        int f = i * 256 + t;            // uint4 index, 3584 total (32 per row)
        int r = f >> 5, pos = f & 31;
        *(uint4*)(wt_s + r * WT_STRIDE + pos * 8) = ((const uint4*)WtG)[f];
    }

    floatx4 acc[7] = {};

    for (int step = 0; step < 8; ++step) {
        const int k0 = step * 32;
        __syncthreads();
        #pragma unroll
        for (int i = 0; i < 2; ++i) {
            int idx = i * 256 + t;       // 512 float4 total
            int r = idx >> 3, c4 = idx & 7;
            int gr = rowBase + r; if (gr >= N) gr = N - 1;
            float4 v = *(const float4*)(x + (size_t)gr * FIN + k0 + c4 * 4);
            ushort4 u;
            u.x = (unsigned short)(__float_as_uint(v.x) >> 16);
            u.y = (unsigned short)(__float_as_uint(v.y) >> 16);
            u.z = (unsigned short)(__float_as_uint(v.z) >> 16);
            u.w = (unsigned short)(__float_as_uint(v.w) >> 16);
            *(ushort4*)(xa_s + r * XA_STRIDE + c4 * 4) = u;
        }
        __syncthreads();
        short8 a = *(const short8*)(xa_s + ((wv << 4) + ln) * XA_STRIDE + qd * 8);
        #pragma unroll
        for (int ct = 0; ct < 7; ++ct) {
            short8 b = *(const short8*)(wt_s + (ct * 16 + ln) * WT_STRIDE + k0 + qd * 8);
            acc[ct] = __builtin_amdgcn_mfma_f32_16x16x32_bf16(a, b, acc[ct], 0, 0, 0);
        }
    }

    // C/D: col = ln, row = qd*4 + r
    #pragma unroll
    for (int ct = 0; ct < 7; ++ct) {
        #pragma unroll
        for (int r = 0; r < 4; ++r) {
            int gr   = rowBase + (wv << 4) + (qd << 2) + r;
            int colg = ct * 16 + ln;
            if (gr < N && colg < HC)
                xhb[(size_t)gr * HC + colg] = (unsigned short)bf16r(acc[ct][r]);
        }
    }
}

// layer-1 pack: per (n,h) build 16B record {7 msg bf16, src-logit bf16} + aldst f32
__global__ void k_pack1(const unsigned short* __restrict__ xhb,
                        const float* __restrict__ asrc, const float* __restrict__ adst,
                        uint4* __restrict__ xpack, float* __restrict__ aldst, int NH)
{
    int id = blockIdx.x * blockDim.x + threadIdx.x;
    if (id >= NH) return;
    int n = id / H, h = id - n * H;
    const unsigned short* xp = xhb + (size_t)n * HC + h * C;
    unsigned v[C];
    float s1 = 0.f, s2 = 0.f;
    #pragma unroll
    for (int c2 = 0; c2 < C; ++c2) {
        v[c2] = xp[c2];
        float f = bflo(v[c2]);
        s1 = fmaf(f, asrc[h * C + c2], s1);
        s2 = fmaf(f, adst[h * C + c2], s2);
    }
    uint4 pk;
    pk.x = v[0] | (v[1] << 16);
    pk.y = v[2] | (v[3] << 16);
    pk.z = v[4] | (v[5] << 16);
    pk.w = v[6] | (bf16r(s1) << 16);
    xpack[id] = pk;
    aldst[id] = s2;
}

// ---------------- layer-2 projection + pack (thread per node) ----------------

__global__ __launch_bounds__(256) void k_proj2_pack(
    const float* __restrict__ h1, const float* __restrict__ W,
    const float* __restrict__ asrc, const float* __restrict__ adst,
    uint4* __restrict__ xpack, float* __restrict__ aldst, int N)
{
    __shared__ float Ws[C * HC];
    __shared__ float as_s[HC], ad_s[HC];
    const int t = threadIdx.x;
    for (int i = t; i < C * HC; i += 256) Ws[i] = W[i];
    if (t < HC) { as_s[t] = asrc[t]; ad_s[t] = adst[t]; }
    __syncthreads();
    int n = blockIdx.x * 256 + t;
    if (n >= N) return;
    float xr[C];
    #pragma unroll
    for (int c2 = 0; c2 < C; ++c2) xr[c2] = h1[(size_t)n * C + c2];
    #pragma unroll
    for (int h = 0; h < H; ++h) {
        float v[C], s1 = 0.f, s2 = 0.f;
        #pragma unroll
        for (int c2 = 0; c2 < C; ++c2) {
            float acc = 0.f;
            #pragma unroll
            for (int k = 0; k < C; ++k)
                acc = fmaf(xr[k], Ws[k * HC + h * C + c2], acc);
            v[c2] = acc;
            s1 = fmaf(acc, as_s[h * C + c2], s1);
            s2 = fmaf(acc, ad_s[h * C + c2], s2);
        }
        uint4 pk;
        pk.x = bf16r(v[0]) | (bf16r(v[1]) << 16);
        pk.y = bf16r(v[2]) | (bf16r(v[3]) << 16);
        pk.z = bf16r(v[4]) | (bf16r(v[5]) << 16);
        pk.w = bf16r(v[6]) | (bf16r(s1) << 16);
        xpack[(size_t)n * H + h] = pk;     // 224 B contiguous per thread
        aldst[(size_t)n * H + h] = s2;
    }
}

// ---------------- fused aggregation ----------------
// thread = (node, head); one 16B packed load per edge, prefetched one iter ahead

template<int LAYER>
__global__ __launch_bounds__(AGG_BLOCK) void k_agg(
    const int* __restrict__ row_ptr, const int* __restrict__ col,
    const uint4* __restrict__ xpack, const float* __restrict__ aldst,
    const float* __restrict__ bias,
    float* __restrict__ h1, float* __restrict__ out, int N)
{
    __shared__ float vals[NPB][HC];
    __shared__ float fv[NPB][C];
    const int t  = threadIdx.x;
    const int nl = t / H;
    const int h  = t - nl * H;
    const int n  = blockIdx.x * NPB + nl;

    if (n < N) {
        const int e0  = row_ptr[n];
        const int deg = row_ptr[n + 1] - e0;
        const float ld = aldst[(size_t)n * H + h];
        float m, den, mx[C];
        uint4 pk = xpack[(size_t)col[e0] * H + h];
        uint4 pkN;
        if (deg > 1) pkN = xpack[(size_t)col[e0 + 1] * H + h];
        {
            float l = bfhi(pk.w) + ld;
            l = (l > 0.f) ? l : NEG_SLOPE * l;
            m = l; den = 1.f;
            mx[0] = bflo(pk.x); mx[1] = bfhi(pk.x);
            mx[2] = bflo(pk.y); mx[3] = bfhi(pk.y);
            mx[4] = bflo(pk.z); mx[5] = bfhi(pk.z);
            mx[6] = bflo(pk.w);
        }
        for (int i = 1; i < deg; ++i) {
            uint4 cur = pkN;
            if (i + 1 < deg) pkN = xpack[(size_t)col[e0 + i + 1] * H + h];  // prefetch
            float l = bfhi(cur.w) + ld;
            l = (l > 0.f) ? l : NEG_SLOPE * l;
            float mn = fmaxf(m, l);
            float r  = __expf(m - mn);
            float p  = __expf(l - mn);
            den = den * r + p;
            mx[0] = fmaxf(mx[0] * r, p * bflo(cur.x));
            mx[1] = fmaxf(mx[1] * r, p * bfhi(cur.x));
            mx[2] = fmaxf(mx[2] * r, p * bflo(cur.y));
            mx[3] = fmaxf(mx[3] * r, p * bfhi(cur.y));
            mx[4] = fmaxf(mx[4] * r, p * bflo(cur.z));
            mx[5] = fmaxf(mx[5] * r, p * bfhi(cur.z));
            mx[6] = fmaxf(mx[6] * r, p * bflo(cur.w));
            m = mn;
        }
        float rd = 1.f / den;
        #pragma unroll
        for (int c2 = 0; c2 < C; ++c2) vals[nl][h * C + c2] = mx[c2] * rd;
    }
    __syncthreads();

    if (t < NPB * C) {
        int nl2 = t / C, c2 = t - nl2 * C;
        int n2 = blockIdx.x * NPB + nl2;
        if (n2 < N) {
            float s = 0.f;
            #pragma unroll
            for (int hh = 0; hh < H; ++hh) s += vals[nl2][hh * C + c2];
            float o = s * (1.f / H) + bias[c2];
            if (LAYER == 1) h1[(size_t)n2 * C + c2] = fmaxf(o, 0.f);
            else            fv[nl2][c2] = o;
        }
    }
    if (LAYER == 2) {
        __syncthreads();
        if (t < NPB) {
            int n2 = blockIdx.x * NPB + t;
            if (n2 < N) {
                float mv = -1e30f;
                #pragma unroll
                for (int c2 = 0; c2 < C; ++c2) mv = fmaxf(mv, fv[t][c2]);
                float lse = 0.f;
                #pragma unroll
                for (int c2 = 0; c2 < C; ++c2) lse += __expf(fv[t][c2] - mv);
                lse = logf(lse);
                #pragma unroll
                for (int c2 = 0; c2 < C; ++c2)
                    out[(size_t)n2 * C + c2] = fv[t][c2] - mv - lse;
            }
        }
    }
}

// ---------------- launch ----------------

static inline size_t align16(size_t v) { return (v + 15) & ~(size_t)15; }

extern "C" void kernel_launch(void* const* d_in, const int* in_sizes, int n_in,
                              void* d_out, int out_size, void* d_ws, size_t ws_size,
                              hipStream_t stream)
{
    const float* x     = (const float*)d_in[0];
    const int*   ei    = (const int*)d_in[1];
    const float* W1    = (const float*)d_in[2];
    const float* asrc1 = (const float*)d_in[3];
    const float* adst1 = (const float*)d_in[4];
    const float* b1    = (const float*)d_in[5];
    const float* W2    = (const float*)d_in[6];
    const float* asrc2 = (const float*)d_in[7];
    const float* adst2 = (const float*)d_in[8];
    const float* b2    = (const float*)d_in[9];

    const int N  = in_sizes[0] / FIN;   // 100000
    const int E  = in_sizes[1] / 2;     // 1600000
    const int ET = E + N;

    char* w = (char*)d_ws;
    uint4* xpack   = (uint4*)w; w += align16((size_t)N * H * 16);   // 22.4 MB
    unsigned short* xhb = (unsigned short*)w; w += align16((size_t)N * HC * 2); // 19.6 MB
    float* aldst   = (float*)w; w += align16((size_t)N * H * 4);    //  5.6 MB
    float* h1      = (float*)w; w += align16((size_t)N * C * 4);    //  2.8 MB
    int*   row_ptr = (int*)w;   w += align16((size_t)(N + 1) * 4);
    int*   deg     = (int*)w;   w += align16((size_t)N * 4);
    int*   cursor  = (int*)w;   w += align16((size_t)N * 4);
    int*   col     = (int*)w;   w += align16((size_t)ET * 4);       //  6.8 MB
    int*   bsum    = (int*)w;   w += align16(1024 * 4);
    unsigned short* WtG = (unsigned short*)w; w += align16((size_t)WT_ROWS * FIN * 2);

    const int g256N  = (N + 255) / 256;
    const int g256E  = (E + 255) / 256;
    const int g256ET = (ET + 255) / 256;
    const int nbA    = (N + 1023) / 1024;
    const int gAgg   = (N + NPB - 1) / NPB;
    const int gMfma  = (N + 63) / 64;
    const int gNH    = (N * H + 255) / 256;

    // CSR build (graph identical across layers; rebuilt each call — no state)
    k_deg_init<<<g256N, 256, 0, stream>>>(deg, N);
    k_deg_count<<<g256E, 256, 0, stream>>>(ei, E, deg);
    k_scanA<<<nbA, 1024, 0, stream>>>(deg, row_ptr, bsum, N);
    k_scanB<<<1, 1024, 0, stream>>>(bsum, nbA);
    k_scanC<<<g256N, 256, 0, stream>>>(row_ptr, bsum, N);
    k_cursor<<<g256N, 256, 0, stream>>>(row_ptr, cursor, N);
    k_scatter<<<g256ET, 256, 0, stream>>>(ei, E, ET, cursor, col);

    // layer 1
    k_convW<<<(WT_ROWS * FIN + 255) / 256, 256, 0, stream>>>(W1, WtG);
    k_proj1_mfma<<<gMfma, 256, 0, stream>>>(x, WtG, xhb, N);
    k_pack1<<<gNH, 256, 0, stream>>>(xhb, asrc1, adst1, xpack, aldst, N * H);
    k_agg<1><<<gAgg, AGG_BLOCK, 0, stream>>>(row_ptr, col, xpack, aldst, b1,
                                             h1, (float*)d_out, N);
    // layer 2
    k_proj2_pack<<<g256N, 256, 0, stream>>>(h1, W2, asrc2, adst2, xpack, aldst, N);
    k_agg<2><<<gAgg, AGG_BLOCK, 0, stream>>>(row_ptr, col, xpack, aldst, b2,
                                             h1, (float*)d_out, N);
}

// Round 6
// 473.816 us; speedup vs baseline: 2.3661x; 1.2853x over previous
//
#include <hip/hip_runtime.h>
#include <math.h>

#define H  14
#define C  7
#define HC 98
#define FIN 256
#define NEG_SLOPE 0.2f
#define NPB 32
#define AGG_BLOCK (NPB * H)   // 448 = 7 full waves

#define BSHIFT 7
#define BSIZE  128
#define NBUCK_MAX 1024

typedef __attribute__((ext_vector_type(8))) short short8;
typedef __attribute__((ext_vector_type(4))) float floatx4;

#define WT_ROWS   112            // 98 cols zero-padded to 7*16
#define WT_STRIDE 264            // 256 + 8 pad (bf16 units)
#define XA_STRIDE 40             // 32 + 8 pad (bf16 units)

// f32 -> bf16 bits, round-to-nearest-even
__device__ __forceinline__ unsigned bf16r(float f) {
    unsigned u = __float_as_uint(f);
    return (u + 0x7FFFu + ((u >> 16) & 1u)) >> 16;
}
__device__ __forceinline__ float bflo(unsigned w) { return __uint_as_float(w << 16); }
__device__ __forceinline__ float bfhi(unsigned w) { return __uint_as_float(w & 0xFFFF0000u); }

// ---------------- bucketed CSR construction (no self loops) ----------------

__global__ void k_zero(int* __restrict__ p, int n) {
    int i = blockIdx.x * blockDim.x + threadIdx.x;
    if (i < n) p[i] = 0;
}

// per-block LDS histogram of dst buckets -> global gcnt
__global__ __launch_bounds__(256) void k_hist(const int* __restrict__ ei, int E,
                                              int* __restrict__ gcnt, int nb) {
    __shared__ int hist[NBUCK_MAX];
    const int t = threadIdx.x;
    for (int i = t; i < nb; i += 256) hist[i] = 0;
    __syncthreads();
    const int stride = gridDim.x * 256;
    for (int e = blockIdx.x * 256 + t; e < E; e += stride)
        atomicAdd(&hist[ei[E + e] >> BSHIFT], 1);
    __syncthreads();
    for (int i = t; i < nb; i += 256)
        if (hist[i]) atomicAdd(gcnt + i, hist[i]);
}

// single-block scan of bucket counts -> boff (exclusive, nb+1), bcur = boff, row_ptr[N] = E
__global__ __launch_bounds__(1024) void k_bscan(const int* __restrict__ gcnt,
                                                int* __restrict__ boff, int* __restrict__ bcur,
                                                int* __restrict__ row_ptr, int nb, int N) {
    __shared__ int sd[1024];
    int t = threadIdx.x;
    int own = (t < nb) ? gcnt[t] : 0;
    sd[t] = own;
    __syncthreads();
    #pragma unroll
    for (int off = 1; off < 1024; off <<= 1) {
        int v = (t >= off) ? sd[t - off] : 0;
        __syncthreads();
        sd[t] += v;
        __syncthreads();
    }
    if (t < nb) {
        boff[t + 1] = sd[t];
        bcur[t] = sd[t] - own;          // exclusive
        if (t == nb - 1) row_ptr[N] = sd[t];
    }
    if (t == 0) boff[0] = 0;
}

// partition edges into bucket-contiguous (src,dst) records with per-block reservations
__global__ __launch_bounds__(256) void k_part(const int* __restrict__ ei, int E,
                                              int* __restrict__ bcur, int2* __restrict__ pedge,
                                              int nb) {
    __shared__ int hist[NBUCK_MAX];
    __shared__ int start[NBUCK_MAX];
    const int t = threadIdx.x;
    const int chunk = (E + gridDim.x - 1) / gridDim.x;
    const int c0 = blockIdx.x * chunk;
    const int c1 = min(c0 + chunk, E);
    for (int i = t; i < nb; i += 256) hist[i] = 0;
    __syncthreads();
    for (int e = c0 + t; e < c1; e += 256)
        atomicAdd(&hist[ei[E + e] >> BSHIFT], 1);
    __syncthreads();
    for (int i = t; i < nb; i += 256) {
        int h = hist[i];
        start[i] = h ? atomicAdd(bcur + i, h) : 0;
        hist[i] = 0;                     // reuse as local cursor
    }
    __syncthreads();
    for (int e = c0 + t; e < c1; e += 256) {
        int s = ei[e], d = ei[E + e];
        int b = d >> BSHIFT;
        int pos = start[b] + atomicAdd(&hist[b], 1);
        pedge[pos] = make_int2(s, d);
    }
}

// per-bucket: count node degrees, scan, write row_ptr, scatter col (L2-local)
__global__ __launch_bounds__(256) void k_bcsr(const int2* __restrict__ pedge,
                                              const int* __restrict__ boff,
                                              int* __restrict__ row_ptr, int* __restrict__ col,
                                              int N) {
    __shared__ int cnt[BSIZE];
    __shared__ int sc[BSIZE];
    __shared__ int cur[BSIZE];
    const int b  = blockIdx.x;
    const int t  = threadIdx.x;
    const int e0 = boff[b], e1 = boff[b + 1];
    const int base = b << BSHIFT;
    const int nv = min(BSIZE, N - base);
    if (t < BSIZE) cnt[t] = 0;
    __syncthreads();
    for (int e = e0 + t; e < e1; e += 256)
        atomicAdd(&cnt[pedge[e].y - base], 1);
    __syncthreads();
    if (t < BSIZE) sc[t] = cnt[t];
    __syncthreads();
    #pragma unroll
    for (int off = 1; off < BSIZE; off <<= 1) {
        int v = 0;
        if (t < BSIZE && t >= off) v = sc[t - off];
        __syncthreads();
        if (t < BSIZE) sc[t] += v;
        __syncthreads();
    }
    if (t < nv) {
        int excl = sc[t] - cnt[t];
        row_ptr[base + t] = e0 + excl;
        cur[t] = excl;
    }
    __syncthreads();
    for (int e = e0 + t; e < e1; e += 256) {
        int2 r = pedge[e];
        int d = r.y - base;
        int pos = e0 + atomicAdd(&cur[d], 1);
        col[pos] = r.x;
    }
}

// ---------------- layer-1 projection via MFMA ----------------

// W1 [256][98] f32  ->  Wt bf16 [112][256] (transposed, zero-padded cols)
__global__ void k_convW(const float* __restrict__ W, unsigned short* __restrict__ WtG) {
    int id = blockIdx.x * blockDim.x + threadIdx.x;   // 112*256
    int n = id >> 8, k = id & 255;
    float v = (n < HC) ? W[k * HC + n] : 0.f;
    WtG[id] = (unsigned short)(__float_as_uint(v) >> 16);  // exact: inputs bf16-rounded
}

// xhb(bf16)[N][98] = x @ W1 using mfma_f32_16x16x32_bf16
__global__ __launch_bounds__(256) void k_proj1_mfma(
    const float* __restrict__ x, const unsigned short* __restrict__ WtG,
    unsigned short* __restrict__ xhb, int N)
{
    __shared__ unsigned short wt_s[WT_ROWS * WT_STRIDE];  // 59136 B
    __shared__ unsigned short xa_s[64 * XA_STRIDE];       //  5120 B
    const int t  = threadIdx.x;
    const int wv = t >> 6;
    const int l  = t & 63;
    const int ln = l & 15;
    const int qd = l >> 4;
    const int rowBase = blockIdx.x * 64;

    #pragma unroll
    for (int i = 0; i < 14; ++i) {
        int f = i * 256 + t;            // uint4 index, 3584 total (32 per row)
        int r = f >> 5, pos = f & 31;
        *(uint4*)(wt_s + r * WT_STRIDE + pos * 8) = ((const uint4*)WtG)[f];
    }

    floatx4 acc[7] = {};

    for (int step = 0; step < 8; ++step) {
        const int k0 = step * 32;
        __syncthreads();
        #pragma unroll
        for (int i = 0; i < 2; ++i) {
            int idx = i * 256 + t;       // 512 float4 total
            int r = idx >> 3, c4 = idx & 7;
            int gr = rowBase + r; if (gr >= N) gr = N - 1;
            float4 v = *(const float4*)(x + (size_t)gr * FIN + k0 + c4 * 4);
            ushort4 u;
            u.x = (unsigned short)(__float_as_uint(v.x) >> 16);
            u.y = (unsigned short)(__float_as_uint(v.y) >> 16);
            u.z = (unsigned short)(__float_as_uint(v.z) >> 16);
            u.w = (unsigned short)(__float_as_uint(v.w) >> 16);
            *(ushort4*)(xa_s + r * XA_STRIDE + c4 * 4) = u;
        }
        __syncthreads();
        short8 a = *(const short8*)(xa_s + ((wv << 4) + ln) * XA_STRIDE + qd * 8);
        #pragma unroll
        for (int ct = 0; ct < 7; ++ct) {
            short8 b = *(const short8*)(wt_s + (ct * 16 + ln) * WT_STRIDE + k0 + qd * 8);
            acc[ct] = __builtin_amdgcn_mfma_f32_16x16x32_bf16(a, b, acc[ct], 0, 0, 0);
        }
    }

    // C/D: col = ln, row = qd*4 + r
    #pragma unroll
    for (int ct = 0; ct < 7; ++ct) {
        #pragma unroll
        for (int r = 0; r < 4; ++r) {
            int gr   = rowBase + (wv << 4) + (qd << 2) + r;
            int colg = ct * 16 + ln;
            if (gr < N && colg < HC)
                xhb[(size_t)gr * HC + colg] = (unsigned short)bf16r(acc[ct][r]);
        }
    }
}

// layer-1 pack: per (n,h) build 16B record {7 msg bf16, src-logit bf16} + aldst f32
__global__ void k_pack1(const unsigned short* __restrict__ xhb,
                        const float* __restrict__ asrc, const float* __restrict__ adst,
                        uint4* __restrict__ xpack, float* __restrict__ aldst, int NH)
{
    int id = blockIdx.x * blockDim.x + threadIdx.x;
    if (id >= NH) return;
    int n = id / H, h = id - n * H;
    const unsigned short* xp = xhb + (size_t)n * HC + h * C;
    unsigned v[C];
    float s1 = 0.f, s2 = 0.f;
    #pragma unroll
    for (int c2 = 0; c2 < C; ++c2) {
        v[c2] = xp[c2];
        float f = bflo(v[c2]);
        s1 = fmaf(f, asrc[h * C + c2], s1);
        s2 = fmaf(f, adst[h * C + c2], s2);
    }
    uint4 pk;
    pk.x = v[0] | (v[1] << 16);
    pk.y = v[2] | (v[3] << 16);
    pk.z = v[4] | (v[5] << 16);
    pk.w = v[6] | (bf16r(s1) << 16);
    xpack[id] = pk;
    aldst[id] = s2;
}

// ---------------- layer-2 projection + pack (thread per node) ----------------

__global__ __launch_bounds__(256) void k_proj2_pack(
    const float* __restrict__ h1, const float* __restrict__ W,
    const float* __restrict__ asrc, const float* __restrict__ adst,
    uint4* __restrict__ xpack, float* __restrict__ aldst, int N)
{
    __shared__ float Ws[C * HC];
    __shared__ float as_s[HC], ad_s[HC];
    const int t = threadIdx.x;
    for (int i = t; i < C * HC; i += 256) Ws[i] = W[i];
    if (t < HC) { as_s[t] = asrc[t]; ad_s[t] = adst[t]; }
    __syncthreads();
    int n = blockIdx.x * 256 + t;
    if (n >= N) return;
    float xr[C];
    #pragma unroll
    for (int c2 = 0; c2 < C; ++c2) xr[c2] = h1[(size_t)n * C + c2];
    #pragma unroll
    for (int h = 0; h < H; ++h) {
        float v[C], s1 = 0.f, s2 = 0.f;
        #pragma unroll
        for (int c2 = 0; c2 < C; ++c2) {
            float acc = 0.f;
            #pragma unroll
            for (int k = 0; k < C; ++k)
                acc = fmaf(xr[k], Ws[k * HC + h * C + c2], acc);
            v[c2] = acc;
            s1 = fmaf(acc, as_s[h * C + c2], s1);
            s2 = fmaf(acc, ad_s[h * C + c2], s2);
        }
        uint4 pk;
        pk.x = bf16r(v[0]) | (bf16r(v[1]) << 16);
        pk.y = bf16r(v[2]) | (bf16r(v[3]) << 16);
        pk.z = bf16r(v[4]) | (bf16r(v[5]) << 16);
        pk.w = bf16r(v[6]) | (bf16r(s1) << 16);
        xpack[(size_t)n * H + h] = pk;     // 224 B contiguous per thread
        aldst[(size_t)n * H + h] = s2;
    }
}

// ---------------- fused aggregation ----------------
// thread = (node, head); self-loop initializes state (not stored in CSR);
// one 16B packed load per edge, prefetched one iter ahead

template<int LAYER>
__global__ __launch_bounds__(AGG_BLOCK) void k_agg(
    const int* __restrict__ row_ptr, const int* __restrict__ col,
    const uint4* __restrict__ xpack, const float* __restrict__ aldst,
    const float* __restrict__ bias,
    float* __restrict__ h1, float* __restrict__ out, int N)
{
    __shared__ float vals[NPB][HC];
    __shared__ float fv[NPB][C];
    const int t  = threadIdx.x;
    const int nl = t / H;
    const int h  = t - nl * H;
    const int n  = blockIdx.x * NPB + nl;

    if (n < N) {
        const int e0  = row_ptr[n];
        const int deg = row_ptr[n + 1] - e0;
        const float ld = aldst[(size_t)n * H + h];
        float m, den, mx[C];
        {   // self loop (implicit)
            uint4 pk = xpack[(size_t)n * H + h];
            float l = bfhi(pk.w) + ld;
            l = (l > 0.f) ? l : NEG_SLOPE * l;
            m = l; den = 1.f;
            mx[0] = bflo(pk.x); mx[1] = bfhi(pk.x);
            mx[2] = bflo(pk.y); mx[3] = bfhi(pk.y);
            mx[4] = bflo(pk.z); mx[5] = bfhi(pk.z);
            mx[6] = bflo(pk.w);
        }
        uint4 pkN;
        if (deg > 0) pkN = xpack[(size_t)col[e0] * H + h];
        for (int i = 0; i < deg; ++i) {
            uint4 cur = pkN;
            if (i + 1 < deg) pkN = xpack[(size_t)col[e0 + i + 1] * H + h];  // prefetch
            float l = bfhi(cur.w) + ld;
            l = (l > 0.f) ? l : NEG_SLOPE * l;
            float mn = fmaxf(m, l);
            float r  = __expf(m - mn);
            float p  = __expf(l - mn);
            den = den * r + p;
            mx[0] = fmaxf(mx[0] * r, p * bflo(cur.x));
            mx[1] = fmaxf(mx[1] * r, p * bfhi(cur.x));
            mx[2] = fmaxf(mx[2] * r, p * bflo(cur.y));
            mx[3] = fmaxf(mx[3] * r, p * bfhi(cur.y));
            mx[4] = fmaxf(mx[4] * r, p * bflo(cur.z));
            mx[5] = fmaxf(mx[5] * r, p * bfhi(cur.z));
            mx[6] = fmaxf(mx[6] * r, p * bflo(cur.w));
            m = mn;
        }
        float rd = 1.f / den;
        #pragma unroll
        for (int c2 = 0; c2 < C; ++c2) vals[nl][h * C + c2] = mx[c2] * rd;
    }
    __syncthreads();

    if (t < NPB * C) {
        int nl2 = t / C, c2 = t - nl2 * C;
        int n2 = blockIdx.x * NPB + nl2;
        if (n2 < N) {
            float s = 0.f;
            #pragma unroll
            for (int hh = 0; hh < H; ++hh) s += vals[nl2][hh * C + c2];
            float o = s * (1.f / H) + bias[c2];
            if (LAYER == 1) h1[(size_t)n2 * C + c2] = fmaxf(o, 0.f);
            else            fv[nl2][c2] = o;
        }
    }
    if (LAYER == 2) {
        __syncthreads();
        if (t < NPB) {
            int n2 = blockIdx.x * NPB + t;
            if (n2 < N) {
                float mv = -1e30f;
                #pragma unroll
                for (int c2 = 0; c2 < C; ++c2) mv = fmaxf(mv, fv[t][c2]);
                float lse = 0.f;
                #pragma unroll
                for (int c2 = 0; c2 < C; ++c2) lse += __expf(fv[t][c2] - mv);
                lse = logf(lse);
                #pragma unroll
                for (int c2 = 0; c2 < C; ++c2)
                    out[(size_t)n2 * C + c2] = fv[t][c2] - mv - lse;
            }
        }
    }
}

// ---------------- launch ----------------

static inline size_t align16(size_t v) { return (v + 15) & ~(size_t)15; }

extern "C" void kernel_launch(void* const* d_in, const int* in_sizes, int n_in,
                              void* d_out, int out_size, void* d_ws, size_t ws_size,
                              hipStream_t stream)
{
    const float* x     = (const float*)d_in[0];
    const int*   ei    = (const int*)d_in[1];
    const float* W1    = (const float*)d_in[2];
    const float* asrc1 = (const float*)d_in[3];
    const float* adst1 = (const float*)d_in[4];
    const float* b1    = (const float*)d_in[5];
    const float* W2    = (const float*)d_in[6];
    const float* asrc2 = (const float*)d_in[7];
    const float* adst2 = (const float*)d_in[8];
    const float* b2    = (const float*)d_in[9];

    const int N  = in_sizes[0] / FIN;   // 100000
    const int E  = in_sizes[1] / 2;     // 1600000
    const int nb = (N + BSIZE - 1) >> BSHIFT;   // 782

    char* w = (char*)d_ws;
    uint4* xpack   = (uint4*)w; w += align16((size_t)N * H * 16);   // 22.4 MB
    // shared region: pedge (CSR build) then xhb (proj1->pack1)
    char*  shared  = w;         w += align16((size_t)E * 8 > (size_t)N * HC * 2
                                             ? (size_t)E * 8 : (size_t)N * HC * 2);
    int2*  pedge   = (int2*)shared;
    unsigned short* xhb = (unsigned short*)shared;
    float* aldst   = (float*)w; w += align16((size_t)N * H * 4);    //  5.6 MB
    float* h1      = (float*)w; w += align16((size_t)N * C * 4);    //  2.8 MB
    int*   row_ptr = (int*)w;   w += align16((size_t)(N + 1) * 4);
    int*   col     = (int*)w;   w += align16((size_t)E * 4);        //  6.4 MB
    int*   gcnt    = (int*)w;   w += align16((size_t)nb * 4);
    int*   boff    = (int*)w;   w += align16((size_t)(nb + 1) * 4);
    int*   bcur    = (int*)w;   w += align16((size_t)nb * 4);
    unsigned short* WtG = (unsigned short*)w; w += align16((size_t)WT_ROWS * FIN * 2);

    const int gAgg  = (N + NPB - 1) / NPB;
    const int gMfma = (N + 63) / 64;
    const int gNH   = (N * H + 255) / 256;
    const int g256N = (N + 255) / 256;

    // ---- bucketed CSR build (no self loops; rebuilt every call) ----
    k_zero<<<(nb + 255) / 256, 256, 0, stream>>>(gcnt, nb);
    k_hist<<<256, 256, 0, stream>>>(ei, E, gcnt, nb);
    k_bscan<<<1, 1024, 0, stream>>>(gcnt, boff, bcur, row_ptr, nb, N);
    k_part<<<256, 256, 0, stream>>>(ei, E, bcur, pedge, nb);
    k_bcsr<<<nb, 256, 0, stream>>>(pedge, boff, row_ptr, col, N);

    // ---- layer 1 ----
    k_convW<<<(WT_ROWS * FIN + 255) / 256, 256, 0, stream>>>(W1, WtG);
    k_proj1_mfma<<<gMfma, 256, 0, stream>>>(x, WtG, xhb, N);
    k_pack1<<<gNH, 256, 0, stream>>>(xhb, asrc1, adst1, xpack, aldst, N * H);
    k_agg<1><<<gAgg, AGG_BLOCK, 0, stream>>>(row_ptr, col, xpack, aldst, b1,
                                             h1, (float*)d_out, N);
    // ---- layer 2 ----
    k_proj2_pack<<<g256N, 256, 0, stream>>>(h1, W2, asrc2, adst2, xpack, aldst, N);
    k_agg<2><<<gAgg, AGG_BLOCK, 0, stream>>>(row_ptr, col, xpack, aldst, b2,
                                             h1, (float*)d_out, N);
}